// Round 15
// baseline (33908.151 us; speedup 1.0000x reference)
//
#include <hip/hip_runtime.h>
#include <math.h>

#define B 128
#define H 256
#define V 130
#define L 100
#define G3 768
#define BH (B*H)
#define NWG 256
#define NT 1024

// ---- workspace layout (4-byte words) ----
#define OFF_FLAGS 0               // 8 group counters x 64-int pad
#define OFF_HID   512
#define OFF_Z1    (OFF_HID + BH)
#define OFF_Z2    (OFF_Z1 + 3*B*G3)
#define OFF_G1HA  (OFF_Z2 + 3*B*G3)
#define OFF_G1HB  (OFF_G1HA + 3*BH)
#define OFF_H2A   (OFF_G1HB + 3*BH)
#define OFF_H2B   (OFF_H2A + 3*BH)
#define OFF_CTXA  (OFF_H2B + 3*BH)
#define OFF_CTXB  (OFF_CTXA + BH)
#define OFF_U0    (OFF_CTXB + BH)
#define OFF_U1    (OFF_U0 + 3*BH)
#define OFF_NOTE  (OFF_U1 + 3*BH)
#define OFF_LOG   (OFF_NOTE + 3*BH)   // logits ws: [128 rows][144]

// ---- LDS layout (float offsets) ----
#define LW_CTX 0
#define LW_OUT 19008
#define LX     23328
#define LSIDX  39968
#define S_TOT  39984            // 159,936 B  (<160 KiB, >80 KiB -> 1 WG/CU)

typedef float v4f __attribute__((ext_vector_type(4)));

__device__ __forceinline__ float sigmoidf_(float x) { return 1.0f / (1.0f + expf(-x)); }

// ---- LLC-coherent accessors for cross-WG activations (placement-proof) ----
__device__ __forceinline__ v4f load_coh4(const float* p) {
  v4f v;
  asm volatile("global_load_dwordx4 %0, %1, off sc0 sc1" : "=v"(v) : "v"(p) : "memory");
  return v;  // caller must s_waitcnt vmcnt before use
}
__device__ __forceinline__ float load_coh(const float* p) {
  float v;
  asm volatile("global_load_dword %0, %1, off sc0 sc1" : "=v"(v) : "v"(p) : "memory");
  return v;  // caller must s_waitcnt vmcnt before use
}
__device__ __forceinline__ void store_coh(float* p, float v) {
  asm volatile("global_store_dword %0, %1, off sc0 sc1" :: "v"(p), "v"(v) : "memory");
}
__device__ __forceinline__ void store_coh4(float* p, v4f v) {
  asm volatile("global_store_dwordx4 %0, %1, off sc0 sc1" :: "v"(p), "v"(v) : "memory");
}
__device__ __forceinline__ void waitvm0() {
  asm volatile("s_waitcnt vmcnt(0)" ::: "memory");
}

// ---- L2-warm prefetch: one dword per 64B line, issued wide-parallel.
// HAZARD RULE: the returned value MUST be kept live (pf_keep) until after a
// vmcnt(0) wait (inside gru_g staging or group_barrier), else the dest VGPR
// gets reused and the late writeback clobbers it (round-14 core dump).
__device__ __forceinline__ float pf_line(const float* p) {
  float t;
  asm volatile("global_load_dword %0, %1, off" : "=v"(t) : "v"(p));
  return t;
}
__device__ __forceinline__ void pf_keep(float t) {
  asm volatile("" :: "v"(t));
}
// gru weights: ih cols [0,256) (3g x 8c x 16 lines) + whh (same) = 768 lines
__device__ __forceinline__ float pf_gru(const float* __restrict__ wih,
                                        const float* __restrict__ whh,
                                        int col0, int tid) {
  if (tid >= 768) return 0.f;
  const int r = tid >> 5, li = tid & 31;
  const int gate = r >> 3, cl = col0 + (r & 7);
  const float* p = (li < 16)
      ? wih + (size_t)(gate * 256 + cl) * 512 + (li << 4)
      : whh + (size_t)(gate * 256 + cl) * 256 + ((li - 16) << 4);
  return pf_line(p);
}
// ctx hh weights: 3 gates x 8 cols x 16 lines = 384 lines
__device__ __forceinline__ float pf_ctxhh(const float* __restrict__ whh,
                                          int col0, int tid) {
  if (tid >= 384) return 0.f;
  const int r = tid >> 4, li = tid & 15;
  const int gate = r >> 3, cl = col0 + (r & 7);
  return pf_line(whh + (size_t)(gate * 256 + cl) * 256 + (li << 4));
}

// 8-lane (kq) butterfly sum of 4 accumulators
__device__ __forceinline__ void red8(float& a, float& b, float& c, float& d) {
#pragma unroll
  for (int m = 1; m <= 4; m <<= 1) {
    a += __shfl_xor(a, m);
    b += __shfl_xor(b, m);
    c += __shfl_xor(c, m);
    d += __shfl_xor(d, m);
  }
}

// ---------------------------------------------------------------------------
// Group barrier: 32 WGs per row-group, single LLC counter, thread-0 spin.
// ---------------------------------------------------------------------------
__device__ __forceinline__ void group_barrier(int* c, int target, int tid) {
  waitvm0();
  __syncthreads();
  if (tid == 0) {
    __hip_atomic_fetch_add(c, 1, __ATOMIC_RELAXED, __HIP_MEMORY_SCOPE_AGENT);
    while (__hip_atomic_load(c, __ATOMIC_RELAXED, __HIP_MEMORY_SCOPE_AGENT) < target)
      __builtin_amdgcn_s_sleep(1);
  }
  __syncthreads();
}

// ---------------------------------------------------------------------------
// Shared GRU compute, K=512 (chunk0 = x @ wih cols [0,256); chunk1 = h @ whh).
// Thread: kq=tid&7 (64 k each), row=(tid>>3)&15, col=col0+(tid>>7).
// ---------------------------------------------------------------------------
__device__ __forceinline__ void gru_compute(
    float* smem, const float* __restrict__ wih, const float* __restrict__ whh,
    const float* __restrict__ zadd, const float* __restrict__ bhh,
    float* out0, float* out1, int row0, int col0, int tid)
{
  float* xb = smem + LX;
  const int kq = tid & 7, row_l = (tid >> 3) & 15;
  const int col = col0 + (tid >> 7);
  const int c = kq >> 2, koff = (kq & 3) << 6;
  const float* xs = xb + row_l * 1040 + c * 260 + (kq & 3) * 65;
  const float *wR, *wZ, *wN;
  if (c == 0) {
    wR = wih + (size_t)col * 512 + koff;
    wZ = wih + (size_t)(256 + col) * 512 + koff;
    wN = wih + (size_t)(512 + col) * 512 + koff;
  } else {
    wR = whh + (size_t)col * 256 + koff;
    wZ = whh + (size_t)(256 + col) * 256 + koff;
    wN = whh + (size_t)(512 + col) * 256 + koff;
  }
  float aR = 0.f, aZ = 0.f, aN = 0.f;
#pragma unroll
  for (int j = 0; j < 64; j += 4) {
    v4f xv = *reinterpret_cast<const v4f*>(xs + j);
    v4f vR = *reinterpret_cast<const v4f*>(wR + j);
    v4f vZ = *reinterpret_cast<const v4f*>(wZ + j);
    v4f vN = *reinterpret_cast<const v4f*>(wN + j);
    aR += xv.x * vR.x; aR += xv.y * vR.y; aR += xv.z * vR.z; aR += xv.w * vR.w;
    aZ += xv.x * vZ.x; aZ += xv.y * vZ.y; aZ += xv.z * vZ.z; aZ += xv.w * vZ.w;
    aN += xv.x * vN.x; aN += xv.y * vN.y; aN += xv.z * vN.z; aN += xv.w * vN.w;
  }
  float aNi = (c == 0) ? aN : 0.f;
  float aNh = (c == 0) ? 0.f : aN;
  red8(aR, aZ, aNi, aNh);
  if (kq == 0) {
    const float* zp = zadd + (size_t)(row0 + row_l) * G3;
    const float hold = xb[row_l * 1040 + 260 + (col >> 6) * 65 + (col & 63)];
    const float r2 = sigmoidf_(aR + zp[col] + bhh[col]);
    const float u2 = sigmoidf_(aZ + zp[256 + col] + bhh[256 + col]);
    const float n2 = tanhf(aNi + zp[512 + col] + r2 * (aNh + bhh[512 + col]));
    const float hnew = (1.f - u2) * n2 + u2 * hold;
    const size_t o = (size_t)(row0 + row_l) * H + col;
    store_coh(out0 + o, hnew);
    if (out1) store_coh(out1 + o, hnew);
  }
}

// GRU phase with standard staging (x0 -> chunk0, x1/h_old -> chunk1).
// pfv: prefetch liveness anchor -- consumed after the vmcnt(0) drain.
__device__ void gru_g(const float* x0, const float* x1,
    const float* __restrict__ wih, const float* __restrict__ whh,
    const float* __restrict__ zadd, const float* __restrict__ bhh,
    float* out0, float* out1, float* smem, int row0, int col0, int tid,
    float pfv)
{
  float* xb = smem + LX;
  const int rr = tid >> 6, k4 = (tid & 63) << 2;
  v4f s0 = load_coh4(x0 + (size_t)(row0 + rr) * H + k4);
  v4f s1 = load_coh4(x1 + (size_t)(row0 + rr) * H + k4);
  __syncthreads();          // previous phase done with xbuf
  waitvm0();                // staging AND prefetch drained
  pf_keep(pfv);             // prefetch reg live past the wait (hazard rule)
  const int xo = (k4 >> 6) * 65 + (k4 & 63);
  *reinterpret_cast<v4f*>(xb + rr * 1040 + xo) = s0;
  *reinterpret_cast<v4f*>(xb + rr * 1040 + 260 + xo) = s1;
  __syncthreads();
  gru_compute(smem, wih, whh, zadd, bhh, out0, out1, row0, col0, tid);
}

// ---------------------------------------------------------------------------
// ctx GRU, K=1024, single-pass 4-chunk staging. ih weights (kq<6) from LDS;
// hh weights (kq 6,7) from global cwhh (prefetched).
// ---------------------------------------------------------------------------
__device__ void ctx_phase(const float* u0p, const float* u1p, const float* u2p,
    const float* cop, const float* __restrict__ cwhh,
    const float* __restrict__ cbih, const float* __restrict__ cbhh,
    float* outc, float* smem, int row0, int col0, int tid, float pfv)
{
  float* xb = smem + LX;
  const int rr = tid >> 6, k4 = (tid & 63) << 2;
  const float* xc[4] = {u0p, u1p, u2p, cop};
  v4f stg[4];
#pragma unroll
  for (int c = 0; c < 4; ++c)
    stg[c] = load_coh4(xc[c] + (size_t)(row0 + rr) * H + k4);
  __syncthreads();
  waitvm0();
  pf_keep(pfv);
  const int xo = (k4 >> 6) * 65 + (k4 & 63);
#pragma unroll
  for (int c = 0; c < 4; ++c)
    *reinterpret_cast<v4f*>(xb + rr * 1040 + c * 260 + xo) = stg[c];
  __syncthreads();

  const int kq = tid & 7, row_l = (tid >> 3) & 15;
  const int col_l = tid >> 7;
  const int col = col0 + col_l;
  const int c = kq >> 1, koff = (kq & 1) * 128;
  const float *wR, *wZ, *wN;
  if (kq < 6) {
    const float* base = smem + LW_CTX + (size_t)(col_l * 3) * 792 + kq * 132;
    wR = base; wZ = base + 792; wN = base + 2 * 792;
  } else {
    const int hoff = (kq - 6) * 128;
    wR = cwhh + (size_t)col * 256 + hoff;
    wZ = cwhh + (size_t)(256 + col) * 256 + hoff;
    wN = cwhh + (size_t)(512 + col) * 256 + hoff;
  }
  float aR = 0.f, aZ = 0.f, aN = 0.f;
#pragma unroll
  for (int kb = 0; kb < 2; ++kb) {
    const float* xs = xb + row_l * 1040 + c * 260 + ((koff + kb * 64) >> 6) * 65;
    const float* wRb = wR + kb * 64;
    const float* wZb = wZ + kb * 64;
    const float* wNb = wN + kb * 64;
#pragma unroll
    for (int j = 0; j < 64; j += 4) {
      v4f xv = *reinterpret_cast<const v4f*>(xs + j);
      v4f vR = *reinterpret_cast<const v4f*>(wRb + j);
      v4f vZ = *reinterpret_cast<const v4f*>(wZb + j);
      v4f vN = *reinterpret_cast<const v4f*>(wNb + j);
      aR += xv.x * vR.x; aR += xv.y * vR.y; aR += xv.z * vR.z; aR += xv.w * vR.w;
      aZ += xv.x * vZ.x; aZ += xv.y * vZ.y; aZ += xv.z * vZ.z; aZ += xv.w * vZ.w;
      aN += xv.x * vN.x; aN += xv.y * vN.y; aN += xv.z * vN.z; aN += xv.w * vN.w;
    }
  }
  float aNi = (kq < 6) ? aN : 0.f;
  float aNh = (kq < 6) ? 0.f : aN;
  red8(aR, aZ, aNi, aNh);
  if (kq == 0) {
    const float hold = xb[row_l * 1040 + 3 * 260 + (col >> 6) * 65 + (col & 63)];
    const float r2 = sigmoidf_(aR + cbih[col] + cbhh[col]);
    const float u2 = sigmoidf_(aZ + cbih[256 + col] + cbhh[256 + col]);
    const float n2 = tanhf(aNi + cbih[512 + col] + r2 * (aNh + cbhh[512 + col]));
    store_coh(outc + (size_t)(row0 + row_l) * H + col, (1.f - u2) * n2 + u2 * hold);
  }
}

// ---------------------------------------------------------------------------
// Logits phase (vocab-split): WG `rank` owns vocab rows rank*5..rank*5+4.
// ---------------------------------------------------------------------------
__device__ void logits_phase(const float* u0i, const float* h2i,
    const float* __restrict__ ob, float* logits_ws, float* outp_d,
    float* smem, int row0, int rank, int i3, int tid)
{
  float* xb = smem + LX;
  const int rr = tid >> 6, k4 = (tid & 63) << 2;
  v4f a4 = load_coh4(u0i + (size_t)(row0 + rr) * H + k4);
  v4f b4 = load_coh4(h2i + (size_t)(row0 + rr) * H + k4);
  __syncthreads();
  waitvm0();
  const int xo = (k4 >> 6) * 65 + (k4 & 63);
  *reinterpret_cast<v4f*>(xb + rr * 1040 + xo) = a4 + b4;
  __syncthreads();

  const int kq = tid & 7, row = (tid >> 3) & 15, vs = tid >> 7;
  const int v = rank * 5 + vs;
  if (vs < 5 && v < V) {
    const float* xs = xb + row * 1040 + ((kq * 32) >> 6) * 65 + ((kq * 32) & 63);
    const float* wp = smem + LW_OUT + (size_t)((i3 * 5 + vs) * 8 + kq) * 36;
    float acc = 0.f;
#pragma unroll
    for (int j = 0; j < 32; j += 4) {
      v4f xv = *reinterpret_cast<const v4f*>(xs + j);
      v4f wv = *reinterpret_cast<const v4f*>(wp + j);
      acc += xv.x * wv.x; acc += xv.y * wv.y; acc += xv.z * wv.z; acc += xv.w * wv.w;
    }
    acc += __shfl_xor(acc, 1);
    acc += __shfl_xor(acc, 2);
    acc += __shfl_xor(acc, 4);
    if (kq == 0) {
      acc += ob[v];
      store_coh(logits_ws + (size_t)(row0 + row) * 144 + v, acc);
      store_coh(outp_d + (size_t)row * (L * V) + v, acc);
    }
  }
}

// ---------------------------------------------------------------------------
// Unroll phase: per-wave argmax over ws logits (redundant in every WG),
// stage x0 = emb[idx] (+write note), x1 = U0[i], then GRU (gru1 stream-1).
// ---------------------------------------------------------------------------
__device__ void unroll_phase(const float* logits_ws, const float* __restrict__ embi,
    const float* u0i, const float* __restrict__ w1ih, const float* __restrict__ w1hh,
    const float* __restrict__ zadd1, const float* __restrict__ bhh1,
    float* note_i, float* out_u1, float* smem, int row0, int col0, int tid)
{
  float* xb = smem + LX;
  int* sidx = (int*)(smem + LSIDX);
  const int w = tid >> 6, l = tid & 63;
  const float* lr = logits_ws + (size_t)(row0 + w) * 144;
  float c0 = load_coh(lr + l);
  float c1 = load_coh(lr + 64 + l);
  float c2 = -INFINITY;
  if (l < 2) c2 = load_coh(lr + 128 + l);
  waitvm0();
  float bv = c0; int bi = l;
  if (c1 > bv) { bv = c1; bi = 64 + l; }
  if (c2 > bv) { bv = c2; bi = 128 + l; }
#pragma unroll
  for (int off = 32; off; off >>= 1) {
    const float ov = __shfl_down(bv, off);
    const int   oi = __shfl_down(bi, off);
    if (ov > bv || (ov == bv && oi < bi)) { bv = ov; bi = oi; }
  }
  if (l == 0) sidx[w] = bi;
  __syncthreads();

  const int rr = tid >> 6, k4 = (tid & 63) << 2;
  const int idx = sidx[rr];
  v4f e4 = *reinterpret_cast<const v4f*>(embi + (size_t)idx * H + k4);  // emb: RO cached
  v4f u4 = load_coh4(u0i + (size_t)(row0 + rr) * H + k4);
  waitvm0();
  const int xo = (k4 >> 6) * 65 + (k4 & 63);
  *reinterpret_cast<v4f*>(xb + rr * 1040 + xo) = e4;
  *reinterpret_cast<v4f*>(xb + rr * 1040 + 260 + xo) = u4;
  store_coh4(note_i + (size_t)(row0 + rr) * H + k4, e4);
  __syncthreads();
  gru_compute(smem, w1ih, w1hh, zadd1, bhh1, out_u1, nullptr, row0, col0, tid);
}

// ---------------------------------------------------------------------------
// Persistent decode: 8 row-groups (16 rows) x 32 col-WGs (8 cols each),
// group/rank from blockIdx (placement-proof). ctx-ih + out weights in LDS;
// streamed weights L2-warmed by liveness-safe wide-parallel prefetch.
// ---------------------------------------------------------------------------
__global__ __launch_bounds__(NT) void decoder_persistent(
    const float* __restrict__ g1wih, const float* __restrict__ g1whh,
    const float* __restrict__ g1bhh,
    const float* __restrict__ g2wih, const float* __restrict__ g2whh,
    const float* __restrict__ g2bhh,
    const float* __restrict__ cwih, const float* __restrict__ cwhh,
    const float* __restrict__ cbih, const float* __restrict__ cbhh,
    const float* __restrict__ outw, const float* __restrict__ outb,
    const float* __restrict__ emb,
    float* __restrict__ out, float* __restrict__ wsf)
{
  __shared__ float smem[S_TOT];   // 159,936 B -> 1 WG/CU
  int* flags = reinterpret_cast<int*>(wsf) + OFF_FLAGS;
  float* Z1   = wsf + OFF_Z1;
  float* Z2   = wsf + OFF_Z2;
  float* g1h[2] = {wsf + OFF_G1HA, wsf + OFF_G1HB};
  float* h2b[2] = {wsf + OFF_H2A,  wsf + OFF_H2B};
  float* ctx[2] = {wsf + OFF_CTXA, wsf + OFF_CTXB};
  float* U0   = wsf + OFF_U0;
  float* U1   = wsf + OFF_U1;
  float* note = wsf + OFF_NOTE;
  float* LOGW = wsf + OFF_LOG;

  const int tid = threadIdx.x;
  const int g    = blockIdx.x >> 5;   // row-group 0..7 (16 rows each)
  const int rank = blockIdx.x & 31;   // col slice 0..31 (8 cols each)
  const int row0 = g * 16;
  const int col0 = rank * 8;
  int* cnt = flags + g * 64;
  int ep = 0;

  // ---- preload LDS weights (once) ----
  for (int i = tid; i < 24 * 768; i += NT) {
    const int cg = i / 768, rem = i - cg * 768;
    const int kq = rem >> 7, j = rem & 127;
    const int colg = col0 + cg / 3, gg = cg % 3;
    smem[LW_CTX + cg * 792 + kq * 132 + j] =
        cwih[(size_t)(gg * 256 + colg) * 768 + kq * 128 + j];
  }
  for (int i = tid; i < 3 * 5 * 8 * 32; i += NT) {
    const int j = i & 31;
    const int kq = (i >> 5) & 7;
    const int vs = (i >> 8) % 5;
    const int i3 = i / 1280;
    const int v = rank * 5 + vs;
    if (v < V)
      smem[LW_OUT + (size_t)((i3 * 5 + vs) * 8 + kq) * 36 + j] =
          outw[(size_t)i3 * V * H + (size_t)v * H + kq * 32 + j];
  }
  __syncthreads();

  const float* w1ih_1 = g1wih + (size_t)G3 * 512;
  const float* w1hh_1 = g1whh + (size_t)G3 * 256;

  for (int t = 0; t < L; ++t) {
    const int rbk = t & 1, wbk = (t + 1) & 1;
    // ---- phase A: gru1 x3 streams (prefetch own weights before each) ----
    float pv = pf_gru(g1wih, g1whh, col0, tid);
    gru_g(note, g1h[rbk], g1wih, g1whh, Z1, g1bhh,
          g1h[wbk], U0, smem, row0, col0, tid, pv);
    pv = pf_gru(w1ih_1, w1hh_1, col0, tid);
    gru_g(note + BH, g1h[rbk] + BH, w1ih_1, w1hh_1,
          Z1 + (size_t)B * G3, g1bhh + G3,
          g1h[wbk] + BH, U0 + BH, smem, row0, col0, tid, pv);
    pv = pf_gru(g1wih + (size_t)2 * G3 * 512, g1whh + (size_t)2 * G3 * 256, col0, tid);
    gru_g(note + 2 * BH, g1h[rbk] + 2 * BH, g1wih + (size_t)2 * G3 * 512,
          g1whh + (size_t)2 * G3 * 256, Z1 + (size_t)2 * B * G3, g1bhh + 2 * G3,
          g1h[wbk] + 2 * BH, U0 + 2 * BH, smem, row0, col0, tid, pv);
    group_barrier(cnt, (++ep) * 32, tid);
    for (int i = 0; i < 3; ++i) {
      const int jj = 3 * t + i;
      const float* us0 = (0 < i ? U1 : U0);
      const float* us1 = (1 < i ? U1 : U0) + BH;
      const float* us2 = U0 + 2 * BH;
      pv = pf_ctxhh(cwhh, col0, tid);
      ctx_phase(us0, us1, us2, ctx[jj & 1], cwhh, cbih, cbhh,
                ctx[(jj + 1) & 1], smem, row0, col0, tid, pv);
      group_barrier(cnt, (++ep) * 32, tid);
      pv = pf_gru(g2wih + (size_t)i * G3 * 512, g2whh + (size_t)i * G3 * 256, col0, tid);
      gru_g(ctx[(jj + 1) & 1], h2b[rbk] + (size_t)i * BH,
            g2wih + (size_t)i * G3 * 512, g2whh + (size_t)i * G3 * 256,
            Z2 + (size_t)i * B * G3, g2bhh + (size_t)i * G3,
            h2b[wbk] + (size_t)i * BH, nullptr, smem, row0, col0, tid, pv);
      group_barrier(cnt, (++ep) * 32, tid);
      logits_phase(U0 + (size_t)i * BH, h2b[wbk] + (size_t)i * BH,
                   outb + (size_t)i * V, LOGW,
                   out + ((size_t)(i * B + row0) * L + t) * V,
                   smem, row0, rank, i, tid);
      // prefetch unroll's weights; drained by group_barrier's vmcnt(0)
      pv = pf_gru(w1ih_1, w1hh_1, col0, tid);
      group_barrier(cnt, (++ep) * 32, tid);
      pf_keep(pv);   // live past the barrier's vmcnt(0) drain
      unroll_phase(LOGW, emb + (size_t)i * V * H, U0 + (size_t)i * BH,
                   w1ih_1, w1hh_1,
                   Z1 + (size_t)B * G3, g1bhh + G3,
                   note + (size_t)i * BH, U1 + (size_t)i * BH,
                   smem, row0, col0, tid);
      group_barrier(cnt, (++ep) * 32, tid);
    }
  }
}

// ---------------------------------------------------------------------------
// Prologue kernels
// ---------------------------------------------------------------------------
__global__ __launch_bounds__(256) void hid_kernel(
    const float* __restrict__ z, const float* __restrict__ hw,
    const float* __restrict__ hb, float* __restrict__ hidden)
{
  __shared__ float xs[32][260];
  const int tid = threadIdx.x;
  const int r = tid & 31, hc = tid >> 5;
  const int row0 = blockIdx.y * 32;
  const int col = blockIdx.x * 8 + hc;
  for (int jj = tid; jj < 32 * 64; jj += 256) {
    const int rr = jj >> 6, k4 = (jj & 63) << 2;
    *reinterpret_cast<float4*>(&xs[rr][k4]) =
        *reinterpret_cast<const float4*>(z + (size_t)(row0 + rr) * H + k4);
  }
  __syncthreads();
  float acc = 0.f;
  const float* wrow = hw + (size_t)col * H;
#pragma unroll 8
  for (int k = 0; k < 256; k += 4) {
    const float4 xv = *reinterpret_cast<const float4*>(&xs[r][k]);
    const float4 wv = *reinterpret_cast<const float4*>(wrow + k);
    acc += xv.x * wv.x; acc += xv.y * wv.y; acc += xv.z * wv.z; acc += xv.w * wv.w;
  }
  hidden[(size_t)(row0 + r) * H + col] = tanhf(acc + hb[col]);
}

__global__ __launch_bounds__(256) void zpre_kernel(
    const float* __restrict__ z, const float* __restrict__ wih,
    const float* __restrict__ bih, float* __restrict__ zout)
{
  __shared__ float xs[32][260];
  const int tid = threadIdx.x;
  const int r = tid & 31, hc = tid >> 5;
  const int row0 = blockIdx.y * 32;
  const int gr = blockIdx.x * 8 + hc;   // 0..2303
  const int s = gr / G3;
  const int gg = gr - s * G3;
  for (int jj = tid; jj < 32 * 64; jj += 256) {
    const int rr = jj >> 6, k4 = (jj & 63) << 2;
    *reinterpret_cast<float4*>(&xs[rr][k4]) =
        *reinterpret_cast<const float4*>(z + (size_t)(row0 + rr) * H + k4);
  }
  __syncthreads();
  float acc = 0.f;
  const float* wrow = wih + (size_t)gr * 512 + 256;
#pragma unroll 8
  for (int k = 0; k < 256; k += 4) {
    const float4 xv = *reinterpret_cast<const float4*>(&xs[r][k]);
    const float4 wv = *reinterpret_cast<const float4*>(wrow + k);
    acc += xv.x * wv.x; acc += xv.y * wv.y; acc += xv.z * wv.z; acc += xv.w * wv.w;
  }
  zout[((size_t)(s * B + row0 + r)) * G3 + gg] = acc + bih[gr];
}

__global__ __launch_bounds__(256) void init_copy(
    const float* __restrict__ hidden, float* __restrict__ g1h0,
    float* __restrict__ h20, float* __restrict__ ctx0)
{
  const int e = blockIdx.x * 256 + threadIdx.x;
  const float v = hidden[e];
  ctx0[e] = v;
  for (int s = 0; s < 3; ++s) {
    g1h0[(size_t)s * BH + e] = v;
    h20[(size_t)s * BH + e] = v;
  }
}

__global__ __launch_bounds__(256) void init_note(
    const float* __restrict__ emb, float* __restrict__ note)
{
  const int e = blockIdx.x * 256 + threadIdx.x;   // 0..3*B*H
  const int s = e / BH;
  const int c = e & (H - 1);
  note[e] = emb[(size_t)s * V * H + c];
}

__global__ void zero_flags(int* flags) { flags[threadIdx.x] = 0; }

extern "C" void kernel_launch(void* const* d_in, const int* in_sizes, int n_in,
                              void* d_out, int out_size, void* d_ws, size_t ws_size,
                              hipStream_t stream) {
  const float* z     = (const float*)d_in[0];
  const float* g1wih = (const float*)d_in[1];
  const float* g1whh = (const float*)d_in[2];
  const float* g1bih = (const float*)d_in[3];
  const float* g1bhh = (const float*)d_in[4];
  const float* g2wih = (const float*)d_in[5];
  const float* g2whh = (const float*)d_in[6];
  const float* g2bih = (const float*)d_in[7];
  const float* g2bhh = (const float*)d_in[8];
  const float* cwih  = (const float*)d_in[9];
  const float* cwhh  = (const float*)d_in[10];
  const float* cbih  = (const float*)d_in[11];
  const float* cbhh  = (const float*)d_in[12];
  const float* outw  = (const float*)d_in[13];
  const float* outb  = (const float*)d_in[14];
  const float* hidw  = (const float*)d_in[15];
  const float* hidb  = (const float*)d_in[16];
  const float* emb   = (const float*)d_in[17];
  float* out = (float*)d_out;
  float* wsf = (float*)d_ws;
  int* flags = (int*)d_ws;

  const dim3 blk(256);
  hid_kernel<<<dim3(32, 4), blk, 0, stream>>>(z, hidw, hidb, wsf + OFF_HID);
  zpre_kernel<<<dim3(288, 4), blk, 0, stream>>>(z, g1wih, g1bih, wsf + OFF_Z1);
  zpre_kernel<<<dim3(288, 4), blk, 0, stream>>>(z, g2wih, g2bih, wsf + OFF_Z2);
  init_copy<<<128, blk, 0, stream>>>(wsf + OFF_HID, wsf + OFF_G1HA,
                                     wsf + OFF_H2A, wsf + OFF_CTXA);
  init_note<<<384, blk, 0, stream>>>(emb, wsf + OFF_NOTE);
  zero_flags<<<1, 512, 0, stream>>>(flags);

  decoder_persistent<<<NWG, NT, 0, stream>>>(
      g1wih, g1whh, g1bhh, g2wih, g2whh, g2bhh,
      cwih, cwhh, cbih, cbhh, outw, outb, emb, out, wsf);
}

// Round 18
// 32939.450 us; speedup vs baseline: 1.0294x; 1.0294x over previous
//
#include <hip/hip_runtime.h>
#include <math.h>

#define B 128
#define H 256
#define V 130
#define L 100
#define G3 768
#define BH (B*H)
#define NWG 256
#define NT 1024

// ---- workspace layout (4-byte words) ----
#define OFF_FLAGS 0               // 8 group counters x 64-int pad
#define OFF_HID   512
#define OFF_Z1    (OFF_HID + BH)
#define OFF_Z2    (OFF_Z1 + 3*B*G3)
#define OFF_G1HA  (OFF_Z2 + 3*B*G3)
#define OFF_G1HB  (OFF_G1HA + 3*BH)
#define OFF_H2A   (OFF_G1HB + 3*BH)
#define OFF_H2B   (OFF_H2A + 3*BH)
#define OFF_CTXA  (OFF_H2B + 3*BH)
#define OFF_CTXB  (OFF_CTXA + BH)
#define OFF_U0    (OFF_CTXB + BH)
#define OFF_U1    (OFF_U0 + 3*BH)
#define OFF_NOTE  (OFF_U1 + 3*BH)
#define OFF_LOG   (OFF_NOTE + 3*BH)   // logits ws: [128 rows][144]

// ---- LDS layout (float offsets) ----
// LW_CTX: ctx ih weights, 24 (col*3+gate) x [6 kq][132] (128 data + 4 pad)
// LW_OUT: out weights, 3 i x 5 vslot x [8 kq][36] (32 data + 4 pad)
// LX    : xbuf 16 rows x 1040 (4 chunks x 4 sub-rows x 65)
// LSIDX : 16 ints (argmax results)
#define LW_CTX 0
#define LW_OUT 19008
#define LX     23328
#define LSIDX  39968
#define S_TOT  39984            // 159,936 B  (<160 KiB, >80 KiB -> 1 WG/CU)

typedef float v4f __attribute__((ext_vector_type(4)));

__device__ __forceinline__ float sigmoidf_(float x) { return 1.0f / (1.0f + expf(-x)); }

// ---- LLC-coherent accessors for cross-WG activations (placement-proof) ----
__device__ __forceinline__ v4f load_coh4(const float* p) {
  v4f v;
  asm volatile("global_load_dwordx4 %0, %1, off sc0 sc1" : "=v"(v) : "v"(p) : "memory");
  return v;  // caller must s_waitcnt vmcnt before use
}
__device__ __forceinline__ float load_coh(const float* p) {
  float v;
  asm volatile("global_load_dword %0, %1, off sc0 sc1" : "=v"(v) : "v"(p) : "memory");
  return v;  // caller must s_waitcnt vmcnt before use
}
__device__ __forceinline__ void store_coh(float* p, float v) {
  asm volatile("global_store_dword %0, %1, off sc0 sc1" :: "v"(p), "v"(v) : "memory");
}
__device__ __forceinline__ void store_coh4(float* p, v4f v) {
  asm volatile("global_store_dwordx4 %0, %1, off sc0 sc1" :: "v"(p), "v"(v) : "memory");
}
__device__ __forceinline__ void waitvm0() {
  asm volatile("s_waitcnt vmcnt(0)" ::: "memory");
}

// 8-lane (kq) butterfly sum of 4 accumulators
__device__ __forceinline__ void red8(float& a, float& b, float& c, float& d) {
#pragma unroll
  for (int m = 1; m <= 4; m <<= 1) {
    a += __shfl_xor(a, m);
    b += __shfl_xor(b, m);
    c += __shfl_xor(c, m);
    d += __shfl_xor(d, m);
  }
}

// ---------------------------------------------------------------------------
// Group barrier: 32 WGs per row-group, single LLC counter, thread-0 spin.
// ---------------------------------------------------------------------------
__device__ __forceinline__ void group_barrier(int* c, int target, int tid) {
  waitvm0();
  __syncthreads();
  if (tid == 0) {
    __hip_atomic_fetch_add(c, 1, __ATOMIC_RELAXED, __HIP_MEMORY_SCOPE_AGENT);
    while (__hip_atomic_load(c, __ATOMIC_RELAXED, __HIP_MEMORY_SCOPE_AGENT) < target)
      __builtin_amdgcn_s_sleep(1);
  }
  __syncthreads();
}

// ---------------------------------------------------------------------------
// Shared GRU compute, K=512 (chunk0 = x @ wih cols [0,256); chunk1 = h @ whh).
// Thread: kq=tid&7 (64 k each), row=(tid>>3)&15, col=col0+(tid>>7).
// ---------------------------------------------------------------------------
__device__ __forceinline__ void gru_compute(
    float* smem, const float* __restrict__ wih, const float* __restrict__ whh,
    const float* __restrict__ zadd, const float* __restrict__ bhh,
    float* out0, float* out1, int row0, int col0, int tid)
{
  float* xb = smem + LX;
  const int kq = tid & 7, row_l = (tid >> 3) & 15;
  const int col = col0 + (tid >> 7);
  const int c = kq >> 2, koff = (kq & 3) << 6;
  const float* xs = xb + row_l * 1040 + c * 260 + (kq & 3) * 65;
  const float *wR, *wZ, *wN;
  if (c == 0) {
    wR = wih + (size_t)col * 512 + koff;
    wZ = wih + (size_t)(256 + col) * 512 + koff;
    wN = wih + (size_t)(512 + col) * 512 + koff;
  } else {
    wR = whh + (size_t)col * 256 + koff;
    wZ = whh + (size_t)(256 + col) * 256 + koff;
    wN = whh + (size_t)(512 + col) * 256 + koff;
  }
  float aR = 0.f, aZ = 0.f, aN = 0.f;
#pragma unroll
  for (int j = 0; j < 64; j += 4) {
    v4f xv = *reinterpret_cast<const v4f*>(xs + j);
    v4f vR = *reinterpret_cast<const v4f*>(wR + j);
    v4f vZ = *reinterpret_cast<const v4f*>(wZ + j);
    v4f vN = *reinterpret_cast<const v4f*>(wN + j);
    aR += xv.x * vR.x; aR += xv.y * vR.y; aR += xv.z * vR.z; aR += xv.w * vR.w;
    aZ += xv.x * vZ.x; aZ += xv.y * vZ.y; aZ += xv.z * vZ.z; aZ += xv.w * vZ.w;
    aN += xv.x * vN.x; aN += xv.y * vN.y; aN += xv.z * vN.z; aN += xv.w * vN.w;
  }
  float aNi = (c == 0) ? aN : 0.f;
  float aNh = (c == 0) ? 0.f : aN;
  red8(aR, aZ, aNi, aNh);
  if (kq == 0) {
    const float* zp = zadd + (size_t)(row0 + row_l) * G3;
    const float hold = xb[row_l * 1040 + 260 + (col >> 6) * 65 + (col & 63)];
    const float r2 = sigmoidf_(aR + zp[col] + bhh[col]);
    const float u2 = sigmoidf_(aZ + zp[256 + col] + bhh[256 + col]);
    const float n2 = tanhf(aNi + zp[512 + col] + r2 * (aNh + bhh[512 + col]));
    const float hnew = (1.f - u2) * n2 + u2 * hold;
    const size_t o = (size_t)(row0 + row_l) * H + col;
    store_coh(out0 + o, hnew);
    if (out1) store_coh(out1 + o, hnew);
  }
}

// GRU phase with standard staging (x0 -> chunk0, x1/h_old -> chunk1).
__device__ void gru_g(const float* x0, const float* x1,
    const float* __restrict__ wih, const float* __restrict__ whh,
    const float* __restrict__ zadd, const float* __restrict__ bhh,
    float* out0, float* out1, float* smem, int row0, int col0, int tid)
{
  float* xb = smem + LX;
  const int rr = tid >> 6, k4 = (tid & 63) << 2;
  v4f s0 = load_coh4(x0 + (size_t)(row0 + rr) * H + k4);
  v4f s1 = load_coh4(x1 + (size_t)(row0 + rr) * H + k4);
  __syncthreads();          // previous phase done with xbuf
  waitvm0();
  const int xo = (k4 >> 6) * 65 + (k4 & 63);
  *reinterpret_cast<v4f*>(xb + rr * 1040 + xo) = s0;
  *reinterpret_cast<v4f*>(xb + rr * 1040 + 260 + xo) = s1;
  __syncthreads();
  gru_compute(smem, wih, whh, zadd, bhh, out0, out1, row0, col0, tid);
}

// ---------------------------------------------------------------------------
// ctx GRU, K=1024, single-pass 4-chunk staging. ih weights (kq<6) from LDS;
// hh weights (kq 6,7) from global cwhh. Thread k-range [kq*128, kq*128+128).
// ---------------------------------------------------------------------------
__device__ void ctx_phase(const float* u0p, const float* u1p, const float* u2p,
    const float* cop, const float* __restrict__ cwhh,
    const float* __restrict__ cbih, const float* __restrict__ cbhh,
    float* outc, float* smem, int row0, int col0, int tid)
{
  float* xb = smem + LX;
  const int rr = tid >> 6, k4 = (tid & 63) << 2;
  const float* xc[4] = {u0p, u1p, u2p, cop};
  v4f stg[4];
#pragma unroll
  for (int c = 0; c < 4; ++c)
    stg[c] = load_coh4(xc[c] + (size_t)(row0 + rr) * H + k4);
  __syncthreads();
  waitvm0();
  const int xo = (k4 >> 6) * 65 + (k4 & 63);
#pragma unroll
  for (int c = 0; c < 4; ++c)
    *reinterpret_cast<v4f*>(xb + rr * 1040 + c * 260 + xo) = stg[c];
  __syncthreads();

  const int kq = tid & 7, row_l = (tid >> 3) & 15;
  const int col_l = tid >> 7;
  const int col = col0 + col_l;
  const int c = kq >> 1, koff = (kq & 1) * 128;
  const float *wR, *wZ, *wN;
  if (kq < 6) {
    const float* base = smem + LW_CTX + (size_t)(col_l * 3) * 792 + kq * 132;
    wR = base; wZ = base + 792; wN = base + 2 * 792;
  } else {
    const int hoff = (kq - 6) * 128;
    wR = cwhh + (size_t)col * 256 + hoff;
    wZ = cwhh + (size_t)(256 + col) * 256 + hoff;
    wN = cwhh + (size_t)(512 + col) * 256 + hoff;
  }
  float aR = 0.f, aZ = 0.f, aN = 0.f;
#pragma unroll
  for (int kb = 0; kb < 2; ++kb) {
    const float* xs = xb + row_l * 1040 + c * 260 + ((koff + kb * 64) >> 6) * 65;
    const float* wRb = wR + kb * 64;
    const float* wZb = wZ + kb * 64;
    const float* wNb = wN + kb * 64;
#pragma unroll
    for (int j = 0; j < 64; j += 4) {
      v4f xv = *reinterpret_cast<const v4f*>(xs + j);
      v4f vR = *reinterpret_cast<const v4f*>(wRb + j);
      v4f vZ = *reinterpret_cast<const v4f*>(wZb + j);
      v4f vN = *reinterpret_cast<const v4f*>(wNb + j);
      aR += xv.x * vR.x; aR += xv.y * vR.y; aR += xv.z * vR.z; aR += xv.w * vR.w;
      aZ += xv.x * vZ.x; aZ += xv.y * vZ.y; aZ += xv.z * vZ.z; aZ += xv.w * vZ.w;
      aN += xv.x * vN.x; aN += xv.y * vN.y; aN += xv.z * vN.z; aN += xv.w * vN.w;
    }
  }
  float aNi = (kq < 6) ? aN : 0.f;
  float aNh = (kq < 6) ? 0.f : aN;
  red8(aR, aZ, aNi, aNh);
  if (kq == 0) {
    const float hold = xb[row_l * 1040 + 3 * 260 + (col >> 6) * 65 + (col & 63)];
    const float r2 = sigmoidf_(aR + cbih[col] + cbhh[col]);
    const float u2 = sigmoidf_(aZ + cbih[256 + col] + cbhh[256 + col]);
    const float n2 = tanhf(aNi + cbih[512 + col] + r2 * (aNh + cbhh[512 + col]));
    store_coh(outc + (size_t)(row0 + row_l) * H + col, (1.f - u2) * n2 + u2 * hold);
  }
}

// ---------------------------------------------------------------------------
// Logits phase (vocab-split): WG `rank` owns vocab rows rank*5..rank*5+4.
// xsum = u + h2 staged to xbuf chunk0; out weights from LDS. Writes logits
// to ws (row stride 144) and to d_out.
// ---------------------------------------------------------------------------
__device__ void logits_phase(const float* u0i, const float* h2i,
    const float* __restrict__ ob, float* logits_ws, float* outp_d,
    float* smem, int row0, int rank, int i3, int tid)
{
  float* xb = smem + LX;
  const int rr = tid >> 6, k4 = (tid & 63) << 2;
  v4f a4 = load_coh4(u0i + (size_t)(row0 + rr) * H + k4);
  v4f b4 = load_coh4(h2i + (size_t)(row0 + rr) * H + k4);
  __syncthreads();
  waitvm0();
  const int xo = (k4 >> 6) * 65 + (k4 & 63);
  *reinterpret_cast<v4f*>(xb + rr * 1040 + xo) = a4 + b4;
  __syncthreads();

  const int kq = tid & 7, row = (tid >> 3) & 15, vs = tid >> 7;
  const int v = rank * 5 + vs;
  if (vs < 5 && v < V) {
    const float* xs = xb + row * 1040 + ((kq * 32) >> 6) * 65 + ((kq * 32) & 63);
    const float* wp = smem + LW_OUT + (size_t)((i3 * 5 + vs) * 8 + kq) * 36;
    float acc = 0.f;
#pragma unroll
    for (int j = 0; j < 32; j += 4) {
      v4f xv = *reinterpret_cast<const v4f*>(xs + j);
      v4f wv = *reinterpret_cast<const v4f*>(wp + j);
      acc += xv.x * wv.x; acc += xv.y * wv.y; acc += xv.z * wv.z; acc += xv.w * wv.w;
    }
    acc += __shfl_xor(acc, 1);
    acc += __shfl_xor(acc, 2);
    acc += __shfl_xor(acc, 4);
    if (kq == 0) {
      acc += ob[v];
      store_coh(logits_ws + (size_t)(row0 + row) * 144 + v, acc);
      store_coh(outp_d + (size_t)row * (L * V) + v, acc);
    }
  }
}

// ---------------------------------------------------------------------------
// Unroll phase: per-wave argmax over ws logits (redundant in every WG, bit-
// identical -> deterministic), stage x0 = emb[idx] (+write note), x1 = U0[i],
// then GRU with gru1 stream-1 weights.
// ---------------------------------------------------------------------------
__device__ void unroll_phase(const float* logits_ws, const float* __restrict__ embi,
    const float* u0i, const float* __restrict__ w1ih, const float* __restrict__ w1hh,
    const float* __restrict__ zadd1, const float* __restrict__ bhh1,
    float* note_i, float* out_u1, float* smem, int row0, int col0, int tid)
{
  float* xb = smem + LX;
  int* sidx = (int*)(smem + LSIDX);
  const int w = tid >> 6, l = tid & 63;
  const float* lr = logits_ws + (size_t)(row0 + w) * 144;
  float c0 = load_coh(lr + l);
  float c1 = load_coh(lr + 64 + l);
  float c2 = -INFINITY;
  if (l < 2) c2 = load_coh(lr + 128 + l);
  waitvm0();
  float bv = c0; int bi = l;
  if (c1 > bv) { bv = c1; bi = 64 + l; }
  if (c2 > bv) { bv = c2; bi = 128 + l; }
#pragma unroll
  for (int off = 32; off; off >>= 1) {
    const float ov = __shfl_down(bv, off);
    const int   oi = __shfl_down(bi, off);
    if (ov > bv || (ov == bv && oi < bi)) { bv = ov; bi = oi; }
  }
  if (l == 0) sidx[w] = bi;
  __syncthreads();

  const int rr = tid >> 6, k4 = (tid & 63) << 2;
  const int idx = sidx[rr];
  v4f e4 = *reinterpret_cast<const v4f*>(embi + (size_t)idx * H + k4);  // emb: RO cached
  v4f u4 = load_coh4(u0i + (size_t)(row0 + rr) * H + k4);
  waitvm0();
  const int xo = (k4 >> 6) * 65 + (k4 & 63);
  *reinterpret_cast<v4f*>(xb + rr * 1040 + xo) = e4;
  *reinterpret_cast<v4f*>(xb + rr * 1040 + 260 + xo) = u4;
  store_coh4(note_i + (size_t)(row0 + rr) * H + k4, e4);
  __syncthreads();
  gru_compute(smem, w1ih, w1hh, zadd1, bhh1, out_u1, nullptr, row0, col0, tid);
}

// ---------------------------------------------------------------------------
// Persistent decode: 8 row-groups (16 rows) x 32 col-WGs (8 cols each),
// group/rank from blockIdx (placement-proof). ctx-ih + out weights in LDS.
// ---------------------------------------------------------------------------
__global__ __launch_bounds__(NT) void decoder_persistent(
    const float* __restrict__ g1wih, const float* __restrict__ g1whh,
    const float* __restrict__ g1bhh,
    const float* __restrict__ g2wih, const float* __restrict__ g2whh,
    const float* __restrict__ g2bhh,
    const float* __restrict__ cwih, const float* __restrict__ cwhh,
    const float* __restrict__ cbih, const float* __restrict__ cbhh,
    const float* __restrict__ outw, const float* __restrict__ outb,
    const float* __restrict__ emb,
    float* __restrict__ out, float* __restrict__ wsf)
{
  __shared__ float smem[S_TOT];   // 159,936 B -> 1 WG/CU
  int* flags = reinterpret_cast<int*>(wsf) + OFF_FLAGS;
  float* Z1   = wsf + OFF_Z1;
  float* Z2   = wsf + OFF_Z2;
  float* g1h[2] = {wsf + OFF_G1HA, wsf + OFF_G1HB};
  float* h2b[2] = {wsf + OFF_H2A,  wsf + OFF_H2B};
  float* ctx[2] = {wsf + OFF_CTXA, wsf + OFF_CTXB};
  float* U0   = wsf + OFF_U0;
  float* U1   = wsf + OFF_U1;
  float* note = wsf + OFF_NOTE;
  float* LOGW = wsf + OFF_LOG;

  const int tid = threadIdx.x;
  const int g    = blockIdx.x >> 5;   // row-group 0..7 (16 rows each)
  const int rank = blockIdx.x & 31;   // col slice 0..31 (8 cols each)
  const int row0 = g * 16;
  const int col0 = rank * 8;
  int* cnt = flags + g * 64;
  int ep = 0;

  // ---- preload LDS weights (once) ----
  // ctx ih: lw[(col_l*3+gate)*792 + kq*132 + j] = cwih[(gate*256+col)*768 + kq*128 + j]
  for (int i = tid; i < 24 * 768; i += NT) {
    const int cg = i / 768, rem = i - cg * 768;
    const int kq = rem >> 7, j = rem & 127;
    const int colg = col0 + cg / 3, gg = cg % 3;
    smem[LW_CTX + cg * 792 + kq * 132 + j] =
        cwih[(size_t)(gg * 256 + colg) * 768 + kq * 128 + j];
  }
  // out: lw[((i3*5+vs)*8+kq)*36 + j] = outw[i3][rank*5+vs][kq*32+j]
  for (int i = tid; i < 3 * 5 * 8 * 32; i += NT) {
    const int j = i & 31;
    const int kq = (i >> 5) & 7;
    const int vs = (i >> 8) % 5;
    const int i3 = i / 1280;
    const int v = rank * 5 + vs;
    if (v < V)
      smem[LW_OUT + (size_t)((i3 * 5 + vs) * 8 + kq) * 36 + j] =
          outw[(size_t)i3 * V * H + (size_t)v * H + kq * 32 + j];
  }
  __syncthreads();

  for (int t = 0; t < L; ++t) {
    const int rbk = t & 1, wbk = (t + 1) & 1;
    // ---- phase A: gru1 x3 streams ----
    gru_g(note, g1h[rbk], g1wih, g1whh, Z1, g1bhh,
          g1h[wbk], U0, smem, row0, col0, tid);
    gru_g(note + BH, g1h[rbk] + BH, g1wih + (size_t)G3 * 512,
          g1whh + (size_t)G3 * 256, Z1 + (size_t)B * G3, g1bhh + G3,
          g1h[wbk] + BH, U0 + BH, smem, row0, col0, tid);
    gru_g(note + 2 * BH, g1h[rbk] + 2 * BH, g1wih + (size_t)2 * G3 * 512,
          g1whh + (size_t)2 * G3 * 256, Z1 + (size_t)2 * B * G3, g1bhh + 2 * G3,
          g1h[wbk] + 2 * BH, U0 + 2 * BH, smem, row0, col0, tid);
    group_barrier(cnt, (++ep) * 32, tid);
    for (int i = 0; i < 3; ++i) {
      const int jj = 3 * t + i;
      const float* us0 = (0 < i ? U1 : U0);
      const float* us1 = (1 < i ? U1 : U0) + BH;
      const float* us2 = U0 + 2 * BH;
      ctx_phase(us0, us1, us2, ctx[jj & 1], cwhh, cbih, cbhh,
                ctx[(jj + 1) & 1], smem, row0, col0, tid);
      group_barrier(cnt, (++ep) * 32, tid);
      gru_g(ctx[(jj + 1) & 1], h2b[rbk] + (size_t)i * BH,
            g2wih + (size_t)i * G3 * 512, g2whh + (size_t)i * G3 * 256,
            Z2 + (size_t)i * B * G3, g2bhh + (size_t)i * G3,
            h2b[wbk] + (size_t)i * BH, nullptr, smem, row0, col0, tid);
      group_barrier(cnt, (++ep) * 32, tid);
      logits_phase(U0 + (size_t)i * BH, h2b[wbk] + (size_t)i * BH,
                   outb + (size_t)i * V, LOGW,
                   out + ((size_t)(i * B + row0) * L + t) * V,
                   smem, row0, rank, i, tid);
      group_barrier(cnt, (++ep) * 32, tid);
      unroll_phase(LOGW, emb + (size_t)i * V * H, U0 + (size_t)i * BH,
                   g1wih + (size_t)G3 * 512, g1whh + (size_t)G3 * 256,
                   Z1 + (size_t)B * G3, g1bhh + G3,
                   note + (size_t)i * BH, U1 + (size_t)i * BH,
                   smem, row0, col0, tid);
      group_barrier(cnt, (++ep) * 32, tid);
    }
  }
}

// ---------------------------------------------------------------------------
// Prologue kernels
// ---------------------------------------------------------------------------
__global__ __launch_bounds__(256) void hid_kernel(
    const float* __restrict__ z, const float* __restrict__ hw,
    const float* __restrict__ hb, float* __restrict__ hidden)
{
  __shared__ float xs[32][260];
  const int tid = threadIdx.x;
  const int r = tid & 31, hc = tid >> 5;
  const int row0 = blockIdx.y * 32;
  const int col = blockIdx.x * 8 + hc;
  for (int jj = tid; jj < 32 * 64; jj += 256) {
    const int rr = jj >> 6, k4 = (jj & 63) << 2;
    *reinterpret_cast<float4*>(&xs[rr][k4]) =
        *reinterpret_cast<const float4*>(z + (size_t)(row0 + rr) * H + k4);
  }
  __syncthreads();
  float acc = 0.f;
  const float* wrow = hw + (size_t)col * H;
#pragma unroll 8
  for (int k = 0; k < 256; k += 4) {
    const float4 xv = *reinterpret_cast<const float4*>(&xs[r][k]);
    const float4 wv = *reinterpret_cast<const float4*>(wrow + k);
    acc += xv.x * wv.x; acc += xv.y * wv.y; acc += xv.z * wv.z; acc += xv.w * wv.w;
  }
  hidden[(size_t)(row0 + r) * H + col] = tanhf(acc + hb[col]);
}

__global__ __launch_bounds__(256) void zpre_kernel(
    const float* __restrict__ z, const float* __restrict__ wih,
    const float* __restrict__ bih, float* __restrict__ zout)
{
  __shared__ float xs[32][260];
  const int tid = threadIdx.x;
  const int r = tid & 31, hc = tid >> 5;
  const int row0 = blockIdx.y * 32;
  const int gr = blockIdx.x * 8 + hc;   // 0..2303
  const int s = gr / G3;
  const int gg = gr - s * G3;
  for (int jj = tid; jj < 32 * 64; jj += 256) {
    const int rr = jj >> 6, k4 = (jj & 63) << 2;
    *reinterpret_cast<float4*>(&xs[rr][k4]) =
        *reinterpret_cast<const float4*>(z + (size_t)(row0 + rr) * H + k4);
  }
  __syncthreads();
  float acc = 0.f;
  const float* wrow = wih + (size_t)gr * 512 + 256;
#pragma unroll 8
  for (int k = 0; k < 256; k += 4) {
    const float4 xv = *reinterpret_cast<const float4*>(&xs[r][k]);
    const float4 wv = *reinterpret_cast<const float4*>(wrow + k);
    acc += xv.x * wv.x; acc += xv.y * wv.y; acc += xv.z * wv.z; acc += xv.w * wv.w;
  }
  zout[((size_t)(s * B + row0 + r)) * G3 + gg] = acc + bih[gr];
}

__global__ __launch_bounds__(256) void init_copy(
    const float* __restrict__ hidden, float* __restrict__ g1h0,
    float* __restrict__ h20, float* __restrict__ ctx0)
{
  const int e = blockIdx.x * 256 + threadIdx.x;
  const float v = hidden[e];
  ctx0[e] = v;
  for (int s = 0; s < 3; ++s) {
    g1h0[(size_t)s * BH + e] = v;
    h20[(size_t)s * BH + e] = v;
  }
}

__global__ __launch_bounds__(256) void init_note(
    const float* __restrict__ emb, float* __restrict__ note)
{
  const int e = blockIdx.x * 256 + threadIdx.x;   // 0..3*B*H
  const int s = e / BH;
  const int c = e & (H - 1);
  note[e] = emb[(size_t)s * V * H + c];
}

__global__ void zero_flags(int* flags) { flags[threadIdx.x] = 0; }

extern "C" void kernel_launch(void* const* d_in, const int* in_sizes, int n_in,
                              void* d_out, int out_size, void* d_ws, size_t ws_size,
                              hipStream_t stream) {
  const float* z     = (const float*)d_in[0];
  const float* g1wih = (const float*)d_in[1];
  const float* g1whh = (const float*)d_in[2];
  const float* g1bih = (const float*)d_in[3];
  const float* g1bhh = (const float*)d_in[4];
  const float* g2wih = (const float*)d_in[5];
  const float* g2whh = (const float*)d_in[6];
  const float* g2bih = (const float*)d_in[7];
  const float* g2bhh = (const float*)d_in[8];
  const float* cwih  = (const float*)d_in[9];
  const float* cwhh  = (const float*)d_in[10];
  const float* cbih  = (const float*)d_in[11];
  const float* cbhh  = (const float*)d_in[12];
  const float* outw  = (const float*)d_in[13];
  const float* outb  = (const float*)d_in[14];
  const float* hidw  = (const float*)d_in[15];
  const float* hidb  = (const float*)d_in[16];
  const float* emb   = (const float*)d_in[17];
  float* out = (float*)d_out;
  float* wsf = (float*)d_ws;
  int* flags = (int*)d_ws;

  const dim3 blk(256);
  hid_kernel<<<dim3(32, 4), blk, 0, stream>>>(z, hidw, hidb, wsf + OFF_HID);
  zpre_kernel<<<dim3(288, 4), blk, 0, stream>>>(z, g1wih, g1bih, wsf + OFF_Z1);
  zpre_kernel<<<dim3(288, 4), blk, 0, stream>>>(z, g2wih, g2bih, wsf + OFF_Z2);
  init_copy<<<128, blk, 0, stream>>>(wsf + OFF_HID, wsf + OFF_G1HA,
                                     wsf + OFF_H2A, wsf + OFF_CTXA);
  init_note<<<384, blk, 0, stream>>>(emb, wsf + OFF_NOTE);
  zero_flags<<<1, 512, 0, stream>>>(flags);

  decoder_persistent<<<NWG, NT, 0, stream>>>(
      g1wih, g1whh, g1bhh, g2wih, g2whh, g2bhh,
      cwih, cwhh, cbih, cbhh, outw, outb, emb, out, wsf);
}